// Round 12
// baseline (60.377 us; speedup 1.0000x reference)
//
#include <hip/hip_runtime.h>

typedef __attribute__((ext_vector_type(8))) short bf16x8;
typedef __attribute__((ext_vector_type(4))) float f32x4;

#define GAMMA_ 0.5f
#define LOG2E_ 1.4426950408889634f

constexpr int D      = 256;   // feature dim (K)
constexpr int BM     = 256;   // rows of X per block
constexpr int BN     = 128;   // X_train cols per j-tile
constexpr int BK     = 32;    // K per stage
constexpr int JSPLIT = 8;     // split of M across blockIdx.y

// LDS: 3 ring slots of (A 16KB + B 8KB) + aux panels
constexpr int SLOT      = 24576;
constexpr int AUX_TCOL  = 73728;   // 1024 x f32 (4KB)
constexpr int AUX_COEF  = 77824;   // 1024 x f32 (4KB)
constexpr int AUX_SROW  = 81920;   // 256 x f32 (1KB)
constexpr int LDS_BYTES = 82944;   // 81 KB -> 1 block/CU

// ---------- helpers ----------
__device__ __forceinline__ unsigned short f2bf(float f) {
    unsigned int x = __float_as_uint(f);
    x += 0x7FFFu + ((x >> 16) & 1u);          // RNE
    return (unsigned short)(x >> 16);
}

__device__ __forceinline__ void gload16(void* lds, const void* g) {
    __builtin_amdgcn_global_load_lds(
        (const __attribute__((address_space(1))) void*)g,
        (__attribute__((address_space(3))) void*)lds, 16, 0, 0);
}

// ---------- prep: cast to bf16, row |x|^2, coefs, out-init ----------
__global__ void prep_all_kernel(const float* __restrict__ X,
                                const float* __restrict__ Xt,
                                const float* __restrict__ alphas,
                                const float* __restrict__ y,
                                const float* __restrict__ b,
                                unsigned short* __restrict__ Abf,
                                unsigned short* __restrict__ Bbf,
                                float* __restrict__ srow,
                                float* __restrict__ tcol,
                                float* __restrict__ coef,
                                float* __restrict__ out,
                                int N, int M) {
    int w = threadIdx.x >> 6;         // one wave per row
    int l = threadIdx.x & 63;
    int row = blockIdx.x * 4 + w;
    if (row >= N + M) return;
    const float* src;
    unsigned short* dst;
    if (row < N) { src = X  + (size_t)row * D;       dst = Abf + (size_t)row * D; }
    else         { src = Xt + (size_t)(row - N) * D; dst = Bbf + (size_t)(row - N) * D; }
    const float4 v = reinterpret_cast<const float4*>(src)[l];
    ushort4 u;
    u.x = f2bf(v.x); u.y = f2bf(v.y); u.z = f2bf(v.z); u.w = f2bf(v.w);
    reinterpret_cast<ushort4*>(dst)[l] = u;
    float ss = v.x * v.x + v.y * v.y + v.z * v.z + v.w * v.w;
    #pragma unroll
    for (int off = 32; off >= 1; off >>= 1) ss += __shfl_xor(ss, off);
    if (l == 0) {
        float folded = -GAMMA_ * LOG2E_ * ss;
        if (row < N) { srow[row] = folded; out[row] = b[0]; }
        else {
            int r2 = row - N;
            tcol[r2] = folded;
            coef[r2] = alphas[r2] * y[r2];
        }
    }
}

// ---------- fused RBF-SVM predict: block-wide 3-slot staged pipeline ----------
// pred_i = sum_j exp2( s_i + t_j + (2*g*log2e) * <x_i, xt_j> ) * coef_j + b
// 8 waves (4 row-groups x 2 col-groups), wave tile 64x64, 16 MFMA/stage.
// Stage s = (jt, kt): A(256xBK) + B(128xBK) DMA'd into slot s%3; 2 stages in
// flight, counted vmcnt(3); ONE barrier per stage; frag sets E/O double-buffer
// so DSREAD(s) overlaps MMA(s-1). Loop VMEM = staging ONLY (aux in LDS,
// partial in regs, atomics after the loop).
__launch_bounds__(512, 2)
__global__ void svm_main_kernel(const unsigned short* __restrict__ Abf,
                                const unsigned short* __restrict__ Bbf,
                                const float* __restrict__ srow,
                                const float* __restrict__ tcol,
                                const float* __restrict__ coef,
                                float* __restrict__ out,
                                int M) {
    __shared__ char L[LDS_BYTES];

    const int tid = threadIdx.x;
    const int w   = tid >> 6;          // wave 0..7
    const int l   = tid & 63;
    const int wr  = w >> 1;            // 0..3 : 64-row group
    const int wc  = w & 1;             // 0..1 : 64-col group
    const int hi  = l >> 4;            // 0..3
    const int lo  = l & 15;
    const int row0   = blockIdx.x * BM;
    const int jspan  = M / JSPLIT;     // 1024
    const int jbase  = blockIdx.y * jspan;
    const int NS     = (jspan / BN) * (D / BK);   // 8 jt x 8 kt = 64 stages

    // ---- aux staging: tcol/coef/srow -> LDS, then FULL drain (once) ----
    if (tid < 256) gload16(L + AUX_TCOL + tid * 16,
                           (const char*)(tcol + jbase) + tid * 16);
    else           gload16(L + AUX_COEF + (tid - 256) * 16,
                           (const char*)(coef + jbase) + (tid - 256) * 16);
    if (tid < 64)  gload16(L + AUX_SROW + tid * 16,
                           (const char*)(srow + row0) + tid * 16);
    asm volatile("s_waitcnt vmcnt(0)" ::: "memory");
    __builtin_amdgcn_s_barrier();

    // per-lane row constants (held in regs)
    float sreg[4][4];
    #pragma unroll
    for (int mi = 0; mi < 4; ++mi)
        #pragma unroll
        for (int r = 0; r < 4; ++r)
            sreg[mi][r] = *(const float*)(L + AUX_SROW
                            + (wr * 64 + mi * 16 + hi * 4 + r) * 4);

    const char* Ag = (const char*)Abf + (size_t)row0 * 512;
    const char* Bg = (const char*)Bbf + (size_t)jbase * 512;

    // stage s: A 2 gload16/thread, B 1 gload16/thread (3 vmcnt items/stage)
    auto issue = [&](int s) {
        const int jt = s >> 3, kt = s & 7, sl = s % 3;
        char* base = L + sl * SLOT;
        #pragma unroll
        for (int c = 0; c < 2; ++c) {                  // A: 256 rows x 64B
            int x = c * 8192 + tid * 16;
            int r = x >> 6;
            int src = r * 512 + kt * 64 + ((x & 63) ^ ((r & 3) << 4));
            gload16(base + x, Ag + src);
        }
        {                                              // B: 128 cols x 64B
            int x   = tid * 16;
            int col = x >> 6;
            int src = (jt * BN + col) * 512 + kt * 64 + ((x & 63) ^ ((col & 3) << 4));
            gload16(base + 16384 + x, Bg + src);
        }
    };

    f32x4 acc[4][4];
    #pragma unroll
    for (int mi = 0; mi < 4; ++mi)
        #pragma unroll
        for (int ni = 0; ni < 4; ++ni) {
            f32x4 z = {0.f, 0.f, 0.f, 0.f};
            acc[mi][ni] = z;
        }
    float partial[4][4];
    #pragma unroll
    for (int mi = 0; mi < 4; ++mi)
        #pragma unroll
        for (int r = 0; r < 4; ++r) partial[mi][r] = 0.0f;

    bf16x8 aE[4], bE[4], aO[4], bO[4];   // named frag double-buffer (rule #20)
    const float K2G = 2.0f * GAMMA_ * LOG2E_;

#define DSREAD(SL, AARR, BARR)                                                 \
    {                                                                          \
        _Pragma("unroll")                                                      \
        for (int mi = 0; mi < 4; ++mi) {                                       \
            int rr = wr * 64 + mi * 16 + lo;                                   \
            int off = (SL) * SLOT + rr * 64 + ((hi * 16) ^ ((rr & 3) << 4));   \
            AARR[mi] = *(const bf16x8*)(L + off);                              \
        }                                                                      \
        _Pragma("unroll")                                                      \
        for (int ni = 0; ni < 4; ++ni) {                                       \
            int cc = wc * 64 + ni * 16 + lo;                                   \
            int off = (SL) * SLOT + 16384 + cc * 64                            \
                    + ((hi * 16) ^ ((cc & 3) << 4));                           \
            BARR[ni] = *(const bf16x8*)(L + off);                              \
        }                                                                      \
    }

#define MMA(AARR, BARR)                                                        \
    {                                                                          \
        __builtin_amdgcn_s_setprio(1);                                         \
        _Pragma("unroll")                                                      \
        for (int mi = 0; mi < 4; ++mi)                                         \
            _Pragma("unroll")                                                  \
            for (int ni = 0; ni < 4; ++ni)                                     \
                acc[mi][ni] = __builtin_amdgcn_mfma_f32_16x16x32_bf16(         \
                    AARR[mi], BARR[ni], acc[mi][ni], 0, 0, 0);                 \
        __builtin_amdgcn_s_setprio(0);                                         \
    }

#define ZEROACC                                                                \
    {                                                                          \
        _Pragma("unroll")                                                      \
        for (int mi = 0; mi < 4; ++mi)                                         \
            _Pragma("unroll")                                                  \
            for (int ni = 0; ni < 4; ++ni) {                                   \
                f32x4 z = {0.f, 0.f, 0.f, 0.f};                                \
                acc[mi][ni] = z;                                               \
            }                                                                  \
    }

#define EPILOGUE(JT_)                                                          \
    {                                                                          \
        _Pragma("unroll")                                                      \
        for (int ni = 0; ni < 4; ++ni) {                                       \
            int cl = (JT_) * BN + wc * 64 + ni * 16 + lo;                      \
            float t  = *(const float*)(L + AUX_TCOL + cl * 4);                 \
            float cf = *(const float*)(L + AUX_COEF + cl * 4);                 \
            _Pragma("unroll")                                                  \
            for (int mi = 0; mi < 4; ++mi) {                                   \
                _Pragma("unroll")                                              \
                for (int r = 0; r < 4; ++r) {                                  \
                    float arg = fmaf(acc[mi][ni][r], K2G, sreg[mi][r] + t);    \
                    float p = __builtin_amdgcn_exp2f(arg);                     \
                    partial[mi][r] = fmaf(p, cf, partial[mi][r]);              \
                }                                                              \
            }                                                                  \
        }                                                                      \
    }

    // ---- prologue: 2 stages in flight (6 vmcnt items) ----
    issue(0);
    issue(1);

    for (int ge = 0; ge < NS; ge += 2) {
        // ======== even stage ge: wait ge, read->E, compute stage ge-1 ========
        asm volatile("s_waitcnt vmcnt(3)" ::: "memory");   // stage ge landed
        __builtin_amdgcn_s_barrier();                       // visible block-wide
        if (ge + 2 < NS) issue(ge + 2);                     // slot (ge+2)%3 free
        DSREAD(ge % 3, aE, bE);
        if (ge > 0) { MMA(aO, bO); }                        // stage ge-1
        if (ge > 0 && (ge & 7) == 0) {                      // jt boundary
            EPILOGUE((ge >> 3) - 1);
            ZEROACC;
        }
        // ======== odd stage go=ge+1: wait go, read->O, compute stage ge ======
        {
            const int go = ge + 1;
            if (go + 1 < NS) {
                asm volatile("s_waitcnt vmcnt(3)" ::: "memory");
            } else {
                asm volatile("s_waitcnt vmcnt(0)" ::: "memory");
            }
            __builtin_amdgcn_s_barrier();
            if (go + 2 < NS) issue(go + 2);
            DSREAD(go % 3, aO, bO);
            MMA(aE, bE);                                    // stage ge
        }
    }
    // tail: compute last stage, final j-tile epilogue
    MMA(aO, bO);                                            // stage NS-1
    EPILOGUE((NS >> 3) - 1);

#undef DSREAD
#undef MMA
#undef ZEROACC
#undef EPILOGUE

    // ---- reduce across the 16 lanes of each row group, one atomic per row ----
    #pragma unroll
    for (int mi = 0; mi < 4; ++mi) {
        #pragma unroll
        for (int r = 0; r < 4; ++r) {
            float v = partial[mi][r];
            v += __shfl_xor(v, 1);
            v += __shfl_xor(v, 2);
            v += __shfl_xor(v, 4);
            v += __shfl_xor(v, 8);
            if (lo == 0) {
                int rowg = row0 + wr * 64 + mi * 16 + hi * 4 + r;
                atomicAdd(&out[rowg], v);
            }
        }
    }
}

// ---------- launcher ----------
extern "C" void kernel_launch(void* const* d_in, const int* in_sizes, int n_in,
                              void* d_out, int out_size, void* d_ws, size_t ws_size,
                              hipStream_t stream) {
    const float* X      = (const float*)d_in[0];
    const float* Xt     = (const float*)d_in[1];
    const float* alphas = (const float*)d_in[2];
    const float* y      = (const float*)d_in[3];
    const float* b      = (const float*)d_in[4];
    float* out = (float*)d_out;

    const int N = in_sizes[0] / D;   // 8192
    const int M = in_sizes[1] / D;   // 8192

    // workspace: bf16 X | bf16 Xt | srow[N] | tcol[M] | coef[M]
    char* ws = (char*)d_ws;
    unsigned short* Abf = (unsigned short*)ws;
    unsigned short* Bbf = Abf + (size_t)N * D;
    float* srow = (float*)(Bbf + (size_t)M * D);
    float* tcol = srow + N;
    float* coef = tcol + M;

    prep_all_kernel<<<(N + M) / 4, 256, 0, stream>>>(X, Xt, alphas, y, b,
                                                     Abf, Bbf, srow, tcol, coef,
                                                     out, N, M);

    dim3 grid(N / BM, JSPLIT);   // 32 x 8 = 256 blocks = 1 per CU
    svm_main_kernel<<<grid, 512, 0, stream>>>(Abf, Bbf, srow, tcol, coef, out, M);
}